// Round 6
// baseline (415.466 us; speedup 1.0000x reference)
//
#include <hip/hip_runtime.h>
#include <hip/hip_fp16.h>
#include <math.h>

#define N_NODES 100000
#define N_EDGES 1600000
#define E_TOT   (N_EDGES + N_NODES)

// bucketed CSR build
#define NB     512          // buckets
#define NPB    196          // dst-nodes per bucket (512*196 = 100352 >= N)
#define BCAP   4096         // capacity per bucket (mean 3332, +13 sigma)
#define BIN_CH 4096         // edges per bin_k workgroup
#define NBIN_WG ((E_TOT + BIN_CH - 1) / BIN_CH)

__device__ __forceinline__ float wexp(float v) {
    v = v > 0.f ? v : 0.2f * v;
    return __expf(v);
}

// ---------------------------------------------------------------------------
// GEMM1: h1[N,128] = x[N,128] @ W1[128,128]; fused alpha_src/alpha_dst.
// Alphas in fp32; h1 stored fp16. W1 staged in LDS (64KB).
// ---------------------------------------------------------------------------
__global__ __launch_bounds__(256) void gemm1_k(
    const float* __restrict__ x, const float* __restrict__ W1,
    const float* __restrict__ as1, const float* __restrict__ ad1,
    __half* __restrict__ h1h, float* __restrict__ asrc, float* __restrict__ adst)
{
    __shared__ float4 Ws[128 * 32];
    const int t = threadIdx.x;
    const float4* W4 = (const float4*)W1;
#pragma unroll
    for (int i = 0; i < 16; ++i) Ws[t + i * 256] = W4[t + i * 256];
    __syncthreads();

    const int team = t >> 5;
    const int L    = t & 31;
    const int node0 = blockIdx.x * 32 + team * 4;

    const float* xr0 = x + (size_t)(node0 + 0) * 128;
    const float* xr1 = x + (size_t)(node0 + 1) * 128;
    const float* xr2 = x + (size_t)(node0 + 2) * 128;
    const float* xr3 = x + (size_t)(node0 + 3) * 128;

    float4 accs[4];
#pragma unroll
    for (int i = 0; i < 4; ++i) accs[i] = make_float4(0.f, 0.f, 0.f, 0.f);

    for (int k = 0; k < 128; ++k) {
        float4 w = Ws[k * 32 + L];
        float a = xr0[k], b = xr1[k], c = xr2[k], d = xr3[k];
        accs[0].x += w.x * a; accs[0].y += w.y * a; accs[0].z += w.z * a; accs[0].w += w.w * a;
        accs[1].x += w.x * b; accs[1].y += w.y * b; accs[1].z += w.z * b; accs[1].w += w.w * b;
        accs[2].x += w.x * c; accs[2].y += w.y * c; accs[2].z += w.z * c; accs[2].w += w.w * c;
        accs[3].x += w.x * d; accs[3].y += w.y * d; accs[3].z += w.z * d; accs[3].w += w.w * d;
    }

    float4 as4 = ((const float4*)as1)[L];
    float4 ad4 = ((const float4*)ad1)[L];
#pragma unroll
    for (int nt = 0; nt < 4; ++nt) {
        int node = node0 + nt;
        __half2* row = (__half2*)(h1h + (size_t)node * 128);
        row[2 * L]     = __floats2half2_rn(accs[nt].x, accs[nt].y);
        row[2 * L + 1] = __floats2half2_rn(accs[nt].z, accs[nt].w);
        float ps = accs[nt].x * as4.x + accs[nt].y * as4.y + accs[nt].z * as4.z + accs[nt].w * as4.w;
        float pd = accs[nt].x * ad4.x + accs[nt].y * ad4.y + accs[nt].z * ad4.z + accs[nt].w * ad4.w;
#pragma unroll
        for (int off = 1; off < 16; off <<= 1) {
            ps += __shfl_xor(ps, off);
            pd += __shfl_xor(pd, off);
        }
        if ((L & 15) == 0) {
            int h = L >> 4;
            asrc[node * 2 + h] = ps;
            adst[node * 2 + h] = pd;
        }
    }
}

// ---------------------------------------------------------------------------
// CSR build, phase 1: bin edges by dst bucket.
// ---------------------------------------------------------------------------
__global__ __launch_bounds__(256) void bin_k(
    const int* __restrict__ ei, int* __restrict__ bcur, unsigned* __restrict__ bdata)
{
    __shared__ int hist[NB];
    __shared__ int base[NB];
    const int t = threadIdx.x;
    const int e0 = blockIdx.x * BIN_CH;
    const int n = min(BIN_CH, E_TOT - e0);

    for (int b = t; b < NB; b += 256) hist[b] = 0;
    __syncthreads();

    for (int i = t; i < n; i += 256) {
        int e = e0 + i;
        int d = (e < N_EDGES) ? ei[N_EDGES + e] : e - N_EDGES;
        atomicAdd(&hist[d / NPB], 1);
    }
    __syncthreads();

    for (int b = t; b < NB; b += 256) {
        int c = hist[b];
        base[b] = c ? atomicAdd(&bcur[b], c) : 0;
        hist[b] = 0;      // reuse as local cursor
    }
    __syncthreads();

    for (int i = t; i < n; i += 256) {
        int e = e0 + i;
        int s, d;
        if (e < N_EDGES) { s = ei[e]; d = ei[N_EDGES + e]; }
        else             { s = d = e - N_EDGES; }
        int b  = d / NPB;
        int dl = d - b * NPB;
        int pos = base[b] + atomicAdd(&hist[b], 1);
        if (pos < BCAP)
            bdata[(size_t)b * BCAP + pos] = (unsigned)s | ((unsigned)dl << 17);
    }
}

// ---------------------------------------------------------------------------
// CSR build, phase 2a: exclusive scan of bucket counts (1 wg x 512 threads).
// ---------------------------------------------------------------------------
__global__ __launch_bounds__(512) void scanb_k(
    const int* __restrict__ bcur, int* __restrict__ bbase)
{
    __shared__ int a[NB], b_[NB];
    int t = threadIdx.x;
    int v = bcur[t];
    a[t] = v;
    __syncthreads();
    int* src = a; int* dst = b_;
    for (int off = 1; off < NB; off <<= 1) {
        dst[t] = (t >= off) ? src[t - off] + src[t] : src[t];
        __syncthreads();
        int* tmp = src; src = dst; dst = tmp;
    }
    bbase[t] = src[t] - v;   // exclusive
}

// ---------------------------------------------------------------------------
// CSR build, phase 2b: wg per bucket -> row_start + csr_src (contiguous).
// ---------------------------------------------------------------------------
__global__ __launch_bounds__(256) void build_k(
    const unsigned* __restrict__ bdata, const int* __restrict__ bcur,
    const int* __restrict__ bbase, int* __restrict__ row_start,
    int* __restrict__ csr_src)
{
    __shared__ unsigned rec[BCAP];     // 16 KB
    __shared__ int hist[256];
    __shared__ int excl[NPB];
    __shared__ int lcur[NPB];
    const int t = threadIdx.x;
    const int b = blockIdx.x;
    const int cnt = min(bcur[b], BCAP);
    const int bb = bbase[b];

    hist[t] = 0;
    if (t < NPB) lcur[t] = 0;
    __syncthreads();

    for (int i = t; i < cnt; i += 256) {
        unsigned r = bdata[(size_t)b * BCAP + i];
        rec[i] = r;
        atomicAdd(&hist[r >> 17], 1);
    }
    __syncthreads();

    int v = hist[t];
    __syncthreads();
    for (int off = 1; off < 256; off <<= 1) {
        int y = (t >= off) ? hist[t - off] : 0;
        __syncthreads();
        hist[t] += y;
        __syncthreads();
    }
    if (t < NPB) excl[t] = hist[t] - v;
    __syncthreads();

    int node = b * NPB + t;
    if (t < NPB && node <= N_NODES) row_start[node] = bb + excl[t];

    for (int i = t; i < cnt; i += 256) {
        unsigned r = rec[i];
        int dl = r >> 17;
        int s  = r & 0x1FFFF;
        int slot = atomicAdd(&lcur[dl], 1);
        csr_src[bb + excl[dl] + slot] = s;
    }
}

// ---------------------------------------------------------------------------
// Fused layer-1 aggregation.
// ---------------------------------------------------------------------------
__global__ __launch_bounds__(256) void fagg1_k(
    const int* __restrict__ csr_src, const int* __restrict__ row_start,
    const float* __restrict__ asrc, const float* __restrict__ adst,
    const __half* __restrict__ h1h, const float* __restrict__ b1,
    float* __restrict__ out1)
{
    int node = blockIdx.x * 4 + (threadIdx.x >> 6);
    int L = threadIdx.x & 63;
    int h = L >> 5;
    int b = row_start[node], e = row_start[node + 1];
    const float* as_h = asrc + h;
    float ad = adst[node * 2 + h];
    const __half2* H = (const __half2*)h1h;

    float2 a0 = make_float2(0.f, 0.f), a1 = a0, a2 = a0, a3 = a0;
    float d0 = 0.f, d1 = 0.f, d2 = 0.f, d3 = 0.f;

    int j = b;
    for (; j + 3 < e; j += 4) {
        int s0 = csr_src[j], s1 = csr_src[j + 1], s2 = csr_src[j + 2], s3 = csr_src[j + 3];
        float w0 = wexp(as_h[s0 * 2] + ad);
        float w1 = wexp(as_h[s1 * 2] + ad);
        float w2 = wexp(as_h[s2 * 2] + ad);
        float w3 = wexp(as_h[s3 * 2] + ad);
        float2 x0 = __half22float2(H[(size_t)s0 * 64 + L]);
        float2 x1 = __half22float2(H[(size_t)s1 * 64 + L]);
        float2 x2 = __half22float2(H[(size_t)s2 * 64 + L]);
        float2 x3 = __half22float2(H[(size_t)s3 * 64 + L]);
        a0.x += w0 * x0.x; a0.y += w0 * x0.y; d0 += w0;
        a1.x += w1 * x1.x; a1.y += w1 * x1.y; d1 += w1;
        a2.x += w2 * x2.x; a2.y += w2 * x2.y; d2 += w2;
        a3.x += w3 * x3.x; a3.y += w3 * x3.y; d3 += w3;
    }
    for (; j < e; ++j) {
        int s = csr_src[j];
        float w = wexp(as_h[s * 2] + ad);
        float2 xv = __half22float2(H[(size_t)s * 64 + L]);
        a0.x += w * xv.x; a0.y += w * xv.y; d0 += w;
    }

    float inv = 1.f / (((d0 + d1) + (d2 + d3)) + 1e-16f);
    float2 bb = ((const float2*)b1)[L];
    float vx = (a0.x + a1.x + a2.x + a3.x) * inv + bb.x;
    float vy = (a0.y + a1.y + a2.y + a3.y) * inv + bb.y;
    vx = vx > 0.f ? vx : expm1f(vx);
    vy = vy > 0.f ? vy : expm1f(vy);
    ((float2*)(out1 + (size_t)node * 128))[L] = make_float2(vx, vy);
}

// ---------------------------------------------------------------------------
// GEMM2 (restructured): h2[N,64pad fp16] = in[N,128] @ W2[128,40].
// W2 staged in LDS as Ws[128][64] (cols 40..63 = 0): lane L owns col L;
// read Ws[k*64+L] is 2-lanes/bank = conflict-free. Wave owns 4 nodes;
// per k4: 4 broadcast float4 x-loads + 16 FMA. Fused alpha2 reductions.
// ---------------------------------------------------------------------------
__global__ __launch_bounds__(256) void gemm2_k(
    const float* __restrict__ in, const float* __restrict__ W2,
    const float* __restrict__ as2, const float* __restrict__ ad2,
    __half* __restrict__ h2h, float* __restrict__ asrc, float* __restrict__ adst)
{
    __shared__ float Ws[128 * 64];       // 32 KB
    __shared__ float as_s[64], ad_s[64];
    const int t = threadIdx.x;
    for (int i = t; i < 8192; i += 256) {
        int k = i >> 6, c = i & 63;
        Ws[i] = (c < 40) ? W2[k * 40 + c] : 0.f;
    }
    if (t < 64) {
        as_s[t] = (t < 40) ? as2[t] : 0.f;
        ad_s[t] = (t < 40) ? ad2[t] : 0.f;
    }
    __syncthreads();

    const int wv = t >> 6, L = t & 63;
    const int node0 = blockIdx.x * 16 + wv * 4;

    const float4* r0 = (const float4*)(in + (size_t)(node0 + 0) * 128);
    const float4* r1 = (const float4*)(in + (size_t)(node0 + 1) * 128);
    const float4* r2 = (const float4*)(in + (size_t)(node0 + 2) * 128);
    const float4* r3 = (const float4*)(in + (size_t)(node0 + 3) * 128);

    float acc0 = 0.f, acc1 = 0.f, acc2 = 0.f, acc3 = 0.f;

#pragma unroll 8
    for (int k4 = 0; k4 < 32; ++k4) {
        float4 x0 = r0[k4], x1 = r1[k4], x2 = r2[k4], x3 = r3[k4];
        const float* wk = &Ws[(k4 * 4) * 64 + L];
        float wa = wk[0], wb = wk[64], wc = wk[128], wd = wk[192];
        acc0 += x0.x * wa + x0.y * wb + x0.z * wc + x0.w * wd;
        acc1 += x1.x * wa + x1.y * wb + x1.z * wc + x1.w * wd;
        acc2 += x2.x * wa + x2.y * wb + x2.z * wc + x2.w * wd;
        acc3 += x3.x * wa + x3.y * wb + x3.z * wc + x3.w * wd;
    }

    float accs[4] = {acc0, acc1, acc2, acc3};
#pragma unroll
    for (int nt = 0; nt < 4; ++nt) {
        int node = node0 + nt;
        float a = accs[nt];
        h2h[(size_t)node * 64 + L] = __float2half_rn(a);
        float ps = a * as_s[L];
        float pd = a * ad_s[L];
#pragma unroll
        for (int off = 32; off; off >>= 1) {
            ps += __shfl_xor(ps, off);
            pd += __shfl_xor(pd, off);
        }
        if (L == 0) { asrc[node] = ps; adst[node] = pd; }
    }
}

// ---------------------------------------------------------------------------
// Fused layer-2 aggregation + softmax denom + bias + log_softmax.
// ---------------------------------------------------------------------------
__global__ __launch_bounds__(256) void fagg2_k(
    const int* __restrict__ csr_src, const int* __restrict__ row_start,
    const float* __restrict__ asrc, const float* __restrict__ adst,
    const __half* __restrict__ h2h, const float* __restrict__ b2,
    float* __restrict__ out)
{
    int node = blockIdx.x * 4 + (threadIdx.x >> 6);
    int L = threadIdx.x & 63;
    bool act = L < 40;
    int col = act ? L : 0;
    int b = row_start[node], e = row_start[node + 1];
    float ad = adst[node];

    float a0 = 0.f, a1 = 0.f, a2 = 0.f, a3 = 0.f;
    float d0 = 0.f, d1 = 0.f, d2 = 0.f, d3 = 0.f;

    int j = b;
    for (; j + 3 < e; j += 4) {
        int s0 = csr_src[j], s1 = csr_src[j + 1], s2 = csr_src[j + 2], s3 = csr_src[j + 3];
        float w0 = wexp(asrc[s0] + ad);
        float w1 = wexp(asrc[s1] + ad);
        float w2 = wexp(asrc[s2] + ad);
        float w3 = wexp(asrc[s3] + ad);
        float x0 = __half2float(h2h[(size_t)s0 * 64 + col]);
        float x1 = __half2float(h2h[(size_t)s1 * 64 + col]);
        float x2 = __half2float(h2h[(size_t)s2 * 64 + col]);
        float x3 = __half2float(h2h[(size_t)s3 * 64 + col]);
        a0 += w0 * x0; d0 += w0;
        a1 += w1 * x1; d1 += w1;
        a2 += w2 * x2; d2 += w2;
        a3 += w3 * x3; d3 += w3;
    }
    for (; j < e; ++j) {
        int s = csr_src[j];
        float w = wexp(asrc[s] + ad);
        float xv = __half2float(h2h[(size_t)s * 64 + col]);
        a0 += w * xv; d0 += w;
    }

    float den = (d0 + d1) + (d2 + d3);
    float acc = (a0 + a1) + (a2 + a3);
    float v = act ? acc / (den + 1e-16f) + b2[L] : -1e30f;
    float mx = v;
#pragma unroll
    for (int off = 32; off; off >>= 1) mx = fmaxf(mx, __shfl_xor(mx, off));
    float ex = act ? __expf(v - mx) : 0.f;
#pragma unroll
    for (int off = 32; off; off >>= 1) ex += __shfl_xor(ex, off);
    if (act) out[(size_t)node * 40 + L] = v - mx - logf(ex);
}

// ---------------------------------------------------------------------------
extern "C" void kernel_launch(void* const* d_in, const int* in_sizes, int n_in,
                              void* d_out, int out_size, void* d_ws, size_t ws_size,
                              hipStream_t stream)
{
    const float* x   = (const float*)d_in[0];
    const int*   ei  = (const int*)d_in[1];
    const float* W1  = (const float*)d_in[2];
    const float* as1 = (const float*)d_in[3];
    const float* ad1 = (const float*)d_in[4];
    const float* b1  = (const float*)d_in[5];
    const float* W2  = (const float*)d_in[6];
    const float* as2 = (const float*)d_in[7];
    const float* ad2 = (const float*)d_in[8];
    const float* b2  = (const float*)d_in[9];
    float* out = (float*)d_out;

    float* ws = (float*)d_ws;
    // workspace layout (4B units); total ~23.8M = 95.2 MB
    __half* h1h  = (__half*)ws;                   // N*128 halves; reused as h2h (N*64 halves)
    float* out1  = ws + 6400000;                  // N*128
    float* asrc1 = ws + 19200000;                 // 2N
    float* adst1 = ws + 19400000;                 // 2N
    float* asrc2 = ws + 19600000;                 // N
    float* adst2 = ws + 19700000;                 // N
    int* bcur      = (int*)(ws + 19800000);       // NB
    int* bbase     = (int*)(ws + 19801000);       // NB
    int* row_start = (int*)(ws + 19802000);       // N+1
    int* csr_src   = (int*)(ws + 19910000);       // E_TOT
    unsigned* bdata = (unsigned*)(ws + 21700000); // NB*BCAP = 2.1M

    // zero bucket cursors only (2 KB)
    hipMemsetAsync(bcur, 0, NB * sizeof(int), stream);

    // CSR build: bin -> scan -> build
    bin_k<<<NBIN_WG, 256, 0, stream>>>(ei, bcur, bdata);
    scanb_k<<<1, 512, 0, stream>>>(bcur, bbase);
    build_k<<<NB, 256, 0, stream>>>(bdata, bcur, bbase, row_start, csr_src);

    // layer 1
    gemm1_k<<<3125, 256, 0, stream>>>(x, W1, as1, ad1, h1h, asrc1, adst1);
    fagg1_k<<<25000, 256, 0, stream>>>(csr_src, row_start, asrc1, adst1, h1h, b1, out1);

    // layer 2 (h2h reuses h1h region, stride 64 halves = one 128B line)
    __half* h2h = h1h;
    gemm2_k<<<6250, 256, 0, stream>>>(out1, W2, as2, ad2, h2h, asrc2, adst2);
    fagg2_k<<<25000, 256, 0, stream>>>(csr_src, row_start, asrc2, adst2, h2h, b2, out);
}

// Round 7
// 301.341 us; speedup vs baseline: 1.3787x; 1.3787x over previous
//
#include <hip/hip_runtime.h>
#include <hip/hip_fp16.h>
#include <math.h>

#define N_NODES 100000
#define N_EDGES 1600000
#define E_TOT   (N_EDGES + N_NODES)

// bucketed CSR build
#define NB     512          // buckets
#define NPB    196          // dst-nodes per bucket (512*196 = 100352 >= N)
#define BCAP   4096         // capacity per bucket (mean 3332, +13 sigma)
#define BIN_CH 4096         // edges per bin_k workgroup
#define NBIN_WG ((E_TOT + BIN_CH - 1) / BIN_CH)

__device__ __forceinline__ float wexp(float v) {
    v = v > 0.f ? v : 0.2f * v;
    return __expf(v);
}

// ---------------------------------------------------------------------------
// GEMM1 (LDS-tiled): h1[N,128] = x[N,128] @ W1[128,128], fp16 out; fused
// alpha_src/alpha_dst. Block = 64 nodes; k-tiles of 64. x-tile staged
// COALESCED into LDS (no per-lane broadcast global reads). Thread = 8 nodes
// x 4 cols; per-k: 8 ds_b32 (2 addrs/wave, conflict-free) + 1 ds_b128 + 32 FMA.
// ---------------------------------------------------------------------------
__global__ __launch_bounds__(256) void gemm1_k(
    const float* __restrict__ x, const float* __restrict__ W1,
    const float* __restrict__ as1, const float* __restrict__ ad1,
    __half* __restrict__ h1h, float* __restrict__ asrc, float* __restrict__ adst)
{
    __shared__ float xs[64][65];      // 16.6 KB, stride 65: node-group reads land on distinct banks
    __shared__ float Wsh[64][128];    // 32 KB
    const int t = threadIdx.x;
    const int nbase = blockIdx.x * 64;
    const int c4 = t & 31;            // cols 4*c4 .. 4*c4+3
    const int ng = t >> 5;            // nodes ng*8 .. ng*8+7

    float acc[8][4];
#pragma unroll
    for (int i = 0; i < 8; ++i)
#pragma unroll
        for (int j = 0; j < 4; ++j) acc[i][j] = 0.f;

    for (int kt = 0; kt < 128; kt += 64) {
        __syncthreads();
        // stage x-tile: rows nbase..+63, cols kt..kt+63 (coalesced float4 loads)
        {
            int r = t >> 4;              // 0..15
            int c = (t & 15) * 4;        // 0..60
#pragma unroll
            for (int p = 0; p < 4; ++p) {
                int row = p * 16 + r;
                int gr = nbase + row; if (gr > N_NODES - 1) gr = N_NODES - 1;
                float4 v = *(const float4*)(x + (size_t)gr * 128 + kt + c);
                xs[row][c + 0] = v.x; xs[row][c + 1] = v.y;
                xs[row][c + 2] = v.z; xs[row][c + 3] = v.w;
            }
        }
        // stage W-tile: W1 rows kt..kt+63, all 128 cols (coalesced float4)
        {
            int r = t >> 5;              // 0..7
            int c = (t & 31) * 4;
#pragma unroll
            for (int p = 0; p < 8; ++p) {
                int row = p * 8 + r;
                *(float4*)&Wsh[row][c] = *(const float4*)(W1 + (size_t)(kt + row) * 128 + c);
            }
        }
        __syncthreads();

#pragma unroll 4
        for (int k = 0; k < 64; ++k) {
            float4 w = *(const float4*)&Wsh[k][c4 * 4];
            float x0 = xs[ng * 8 + 0][k], x1 = xs[ng * 8 + 1][k];
            float x2 = xs[ng * 8 + 2][k], x3 = xs[ng * 8 + 3][k];
            float x4 = xs[ng * 8 + 4][k], x5 = xs[ng * 8 + 5][k];
            float x6 = xs[ng * 8 + 6][k], x7 = xs[ng * 8 + 7][k];
            acc[0][0] += x0 * w.x; acc[0][1] += x0 * w.y; acc[0][2] += x0 * w.z; acc[0][3] += x0 * w.w;
            acc[1][0] += x1 * w.x; acc[1][1] += x1 * w.y; acc[1][2] += x1 * w.z; acc[1][3] += x1 * w.w;
            acc[2][0] += x2 * w.x; acc[2][1] += x2 * w.y; acc[2][2] += x2 * w.z; acc[2][3] += x2 * w.w;
            acc[3][0] += x3 * w.x; acc[3][1] += x3 * w.y; acc[3][2] += x3 * w.z; acc[3][3] += x3 * w.w;
            acc[4][0] += x4 * w.x; acc[4][1] += x4 * w.y; acc[4][2] += x4 * w.z; acc[4][3] += x4 * w.w;
            acc[5][0] += x5 * w.x; acc[5][1] += x5 * w.y; acc[5][2] += x5 * w.z; acc[5][3] += x5 * w.w;
            acc[6][0] += x6 * w.x; acc[6][1] += x6 * w.y; acc[6][2] += x6 * w.z; acc[6][3] += x6 * w.w;
            acc[7][0] += x7 * w.x; acc[7][1] += x7 * w.y; acc[7][2] += x7 * w.z; acc[7][3] += x7 * w.w;
        }
    }

    float4 as4 = ((const float4*)as1)[c4];
    float4 ad4 = ((const float4*)ad1)[c4];
#pragma unroll
    for (int i = 0; i < 8; ++i) {
        int node = nbase + ng * 8 + i;
        float ax = acc[i][0], ay = acc[i][1], az = acc[i][2], aw = acc[i][3];
        if (node < N_NODES) {
            __half2* row = (__half2*)(h1h + (size_t)node * 128);
            row[2 * c4]     = __floats2half2_rn(ax, ay);
            row[2 * c4 + 1] = __floats2half2_rn(az, aw);
        }
        float ps = ax * as4.x + ay * as4.y + az * as4.z + aw * as4.w;
        float pd = ax * ad4.x + ay * ad4.y + az * ad4.z + aw * ad4.w;
#pragma unroll
        for (int off = 1; off < 16; off <<= 1) {
            ps += __shfl_xor(ps, off);
            pd += __shfl_xor(pd, off);
        }
        if ((t & 15) == 0 && node < N_NODES) {
            int h = c4 >> 4;
            asrc[node * 2 + h] = ps;
            adst[node * 2 + h] = pd;
        }
    }
}

// ---------------------------------------------------------------------------
// CSR build, phase 1: bin edges by dst bucket.
// ---------------------------------------------------------------------------
__global__ __launch_bounds__(256) void bin_k(
    const int* __restrict__ ei, int* __restrict__ bcur, unsigned* __restrict__ bdata)
{
    __shared__ int hist[NB];
    __shared__ int base[NB];
    const int t = threadIdx.x;
    const int e0 = blockIdx.x * BIN_CH;
    const int n = min(BIN_CH, E_TOT - e0);

    for (int b = t; b < NB; b += 256) hist[b] = 0;
    __syncthreads();

    for (int i = t; i < n; i += 256) {
        int e = e0 + i;
        int d = (e < N_EDGES) ? ei[N_EDGES + e] : e - N_EDGES;
        atomicAdd(&hist[d / NPB], 1);
    }
    __syncthreads();

    for (int b = t; b < NB; b += 256) {
        int c = hist[b];
        base[b] = c ? atomicAdd(&bcur[b], c) : 0;
        hist[b] = 0;      // reuse as local cursor
    }
    __syncthreads();

    for (int i = t; i < n; i += 256) {
        int e = e0 + i;
        int s, d;
        if (e < N_EDGES) { s = ei[e]; d = ei[N_EDGES + e]; }
        else             { s = d = e - N_EDGES; }
        int b  = d / NPB;
        int dl = d - b * NPB;
        int pos = base[b] + atomicAdd(&hist[b], 1);
        if (pos < BCAP)
            bdata[(size_t)b * BCAP + pos] = (unsigned)s | ((unsigned)dl << 17);
    }
}

// ---------------------------------------------------------------------------
// CSR build, phase 2a: exclusive scan of bucket counts (1 wg x 512 threads).
// ---------------------------------------------------------------------------
__global__ __launch_bounds__(512) void scanb_k(
    const int* __restrict__ bcur, int* __restrict__ bbase)
{
    __shared__ int a[NB], b_[NB];
    int t = threadIdx.x;
    int v = bcur[t];
    a[t] = v;
    __syncthreads();
    int* src = a; int* dst = b_;
    for (int off = 1; off < NB; off <<= 1) {
        dst[t] = (t >= off) ? src[t - off] + src[t] : src[t];
        __syncthreads();
        int* tmp = src; src = dst; dst = tmp;
    }
    bbase[t] = src[t] - v;   // exclusive
}

// ---------------------------------------------------------------------------
// CSR build, phase 2b: wg per bucket -> row_start + csr_src (contiguous).
// ---------------------------------------------------------------------------
__global__ __launch_bounds__(256) void build_k(
    const unsigned* __restrict__ bdata, const int* __restrict__ bcur,
    const int* __restrict__ bbase, int* __restrict__ row_start,
    int* __restrict__ csr_src)
{
    __shared__ unsigned rec[BCAP];     // 16 KB
    __shared__ int hist[256];
    __shared__ int excl[NPB];
    __shared__ int lcur[NPB];
    const int t = threadIdx.x;
    const int b = blockIdx.x;
    const int cnt = min(bcur[b], BCAP);
    const int bb = bbase[b];

    hist[t] = 0;
    if (t < NPB) lcur[t] = 0;
    __syncthreads();

    for (int i = t; i < cnt; i += 256) {
        unsigned r = bdata[(size_t)b * BCAP + i];
        rec[i] = r;
        atomicAdd(&hist[r >> 17], 1);
    }
    __syncthreads();

    int v = hist[t];
    __syncthreads();
    for (int off = 1; off < 256; off <<= 1) {
        int y = (t >= off) ? hist[t - off] : 0;
        __syncthreads();
        hist[t] += y;
        __syncthreads();
    }
    if (t < NPB) excl[t] = hist[t] - v;
    __syncthreads();

    int node = b * NPB + t;
    if (t < NPB && node <= N_NODES) row_start[node] = bb + excl[t];

    for (int i = t; i < cnt; i += 256) {
        unsigned r = rec[i];
        int dl = r >> 17;
        int s  = r & 0x1FFFF;
        int slot = atomicAdd(&lcur[dl], 1);
        csr_src[bb + excl[dl] + slot] = s;
    }
}

// ---------------------------------------------------------------------------
// Fused layer-1 aggregation. Writes out1 as fp16 (gemm2 stages fp16->fp32).
// ---------------------------------------------------------------------------
__global__ __launch_bounds__(256) void fagg1_k(
    const int* __restrict__ csr_src, const int* __restrict__ row_start,
    const float* __restrict__ asrc, const float* __restrict__ adst,
    const __half* __restrict__ h1h, const float* __restrict__ b1,
    __half* __restrict__ out1h)
{
    int node = blockIdx.x * 4 + (threadIdx.x >> 6);
    int L = threadIdx.x & 63;
    int h = L >> 5;
    int b = row_start[node], e = row_start[node + 1];
    const float* as_h = asrc + h;
    float ad = adst[node * 2 + h];
    const __half2* H = (const __half2*)h1h;

    float2 a0 = make_float2(0.f, 0.f), a1 = a0, a2 = a0, a3 = a0;
    float d0 = 0.f, d1 = 0.f, d2 = 0.f, d3 = 0.f;

    int j = b;
    for (; j + 3 < e; j += 4) {
        int s0 = csr_src[j], s1 = csr_src[j + 1], s2 = csr_src[j + 2], s3 = csr_src[j + 3];
        float w0 = wexp(as_h[s0 * 2] + ad);
        float w1 = wexp(as_h[s1 * 2] + ad);
        float w2 = wexp(as_h[s2 * 2] + ad);
        float w3 = wexp(as_h[s3 * 2] + ad);
        float2 x0 = __half22float2(H[(size_t)s0 * 64 + L]);
        float2 x1 = __half22float2(H[(size_t)s1 * 64 + L]);
        float2 x2 = __half22float2(H[(size_t)s2 * 64 + L]);
        float2 x3 = __half22float2(H[(size_t)s3 * 64 + L]);
        a0.x += w0 * x0.x; a0.y += w0 * x0.y; d0 += w0;
        a1.x += w1 * x1.x; a1.y += w1 * x1.y; d1 += w1;
        a2.x += w2 * x2.x; a2.y += w2 * x2.y; d2 += w2;
        a3.x += w3 * x3.x; a3.y += w3 * x3.y; d3 += w3;
    }
    for (; j < e; ++j) {
        int s = csr_src[j];
        float w = wexp(as_h[s * 2] + ad);
        float2 xv = __half22float2(H[(size_t)s * 64 + L]);
        a0.x += w * xv.x; a0.y += w * xv.y; d0 += w;
    }

    float inv = 1.f / (((d0 + d1) + (d2 + d3)) + 1e-16f);
    float2 bb = ((const float2*)b1)[L];
    float vx = (a0.x + a1.x + a2.x + a3.x) * inv + bb.x;
    float vy = (a0.y + a1.y + a2.y + a3.y) * inv + bb.y;
    vx = vx > 0.f ? vx : expm1f(vx);
    vy = vy > 0.f ? vy : expm1f(vy);
    ((__half2*)(out1h + (size_t)node * 128))[L] = __floats2half2_rn(vx, vy);
}

// ---------------------------------------------------------------------------
// GEMM2 (LDS-tiled): h2[N,64pad fp16] = out1[N,128] @ W2[128,40] (cols 40..63
// zero). Same skeleton as gemm1: 64-node blocks, k-tiles of 64, coalesced
// fp16 x staging. Thread = 4 nodes x 4 cols. Fused alpha2 reductions.
// ---------------------------------------------------------------------------
__global__ __launch_bounds__(256) void gemm2_k(
    const __half* __restrict__ in1h, const float* __restrict__ W2,
    const float* __restrict__ as2, const float* __restrict__ ad2,
    __half* __restrict__ h2h, float* __restrict__ asrc, float* __restrict__ adst)
{
    __shared__ float xs[64][65];      // 16.6 KB
    __shared__ float Wsh[64][64];     // 16 KB
    __shared__ float as_s[64], ad_s[64];
    const int t = threadIdx.x;
    const int nbase = blockIdx.x * 64;
    const int c4 = t & 15;            // cols 4*c4 .. +3 (of 64)
    const int ng = t >> 4;            // 0..15 -> nodes ng*4 .. +3

    if (t < 64) {
        as_s[t] = (t < 40) ? as2[t] : 0.f;
        ad_s[t] = (t < 40) ? ad2[t] : 0.f;
    }

    float acc[4][4];
#pragma unroll
    for (int i = 0; i < 4; ++i)
#pragma unroll
        for (int j = 0; j < 4; ++j) acc[i][j] = 0.f;

    for (int kt = 0; kt < 128; kt += 64) {
        __syncthreads();
        // stage x-tile from fp16 (coalesced 8B loads)
        {
            int r = t >> 4;              // 0..15
            int c = (t & 15) * 4;        // 0..60
#pragma unroll
            for (int p = 0; p < 4; ++p) {
                int row = p * 16 + r;
                int gr = nbase + row; if (gr > N_NODES - 1) gr = N_NODES - 1;
                const __half2* src = (const __half2*)(in1h + (size_t)gr * 128 + kt + c);
                float2 f01 = __half22float2(src[0]);
                float2 f23 = __half22float2(src[1]);
                xs[row][c + 0] = f01.x; xs[row][c + 1] = f01.y;
                xs[row][c + 2] = f23.x; xs[row][c + 3] = f23.y;
            }
        }
        // stage W2 tile (rows kt..kt+63, 64 cols, zero-padded past 40)
        for (int i = t; i < 4096; i += 256) {
            int k = i >> 6, c = i & 63;
            Wsh[k][c] = (c < 40) ? W2[(size_t)(kt + k) * 40 + c] : 0.f;
        }
        __syncthreads();

#pragma unroll 4
        for (int k = 0; k < 64; ++k) {
            float4 w = *(const float4*)&Wsh[k][c4 * 4];
            float x0 = xs[ng * 4 + 0][k], x1 = xs[ng * 4 + 1][k];
            float x2 = xs[ng * 4 + 2][k], x3 = xs[ng * 4 + 3][k];
            acc[0][0] += x0 * w.x; acc[0][1] += x0 * w.y; acc[0][2] += x0 * w.z; acc[0][3] += x0 * w.w;
            acc[1][0] += x1 * w.x; acc[1][1] += x1 * w.y; acc[1][2] += x1 * w.z; acc[1][3] += x1 * w.w;
            acc[2][0] += x2 * w.x; acc[2][1] += x2 * w.y; acc[2][2] += x2 * w.z; acc[2][3] += x2 * w.w;
            acc[3][0] += x3 * w.x; acc[3][1] += x3 * w.y; acc[3][2] += x3 * w.z; acc[3][3] += x3 * w.w;
        }
    }

    float4 as4 = *(const float4*)&as_s[c4 * 4];
    float4 ad4 = *(const float4*)&ad_s[c4 * 4];
#pragma unroll
    for (int i = 0; i < 4; ++i) {
        int node = nbase + ng * 4 + i;
        float ax = acc[i][0], ay = acc[i][1], az = acc[i][2], aw = acc[i][3];
        if (node < N_NODES) {
            __half2* row = (__half2*)(h2h + (size_t)node * 64);
            row[2 * c4]     = __floats2half2_rn(ax, ay);
            row[2 * c4 + 1] = __floats2half2_rn(az, aw);
        }
        float ps = ax * as4.x + ay * as4.y + az * as4.z + aw * as4.w;
        float pd = ax * ad4.x + ay * ad4.y + az * ad4.z + aw * ad4.w;
#pragma unroll
        for (int off = 1; off < 16; off <<= 1) {
            ps += __shfl_xor(ps, off);
            pd += __shfl_xor(pd, off);
        }
        if ((t & 15) == 0 && node < N_NODES) {
            asrc[node] = ps;
            adst[node] = pd;
        }
    }
}

// ---------------------------------------------------------------------------
// Fused layer-2 aggregation + softmax denom + bias + log_softmax.
// ---------------------------------------------------------------------------
__global__ __launch_bounds__(256) void fagg2_k(
    const int* __restrict__ csr_src, const int* __restrict__ row_start,
    const float* __restrict__ asrc, const float* __restrict__ adst,
    const __half* __restrict__ h2h, const float* __restrict__ b2,
    float* __restrict__ out)
{
    int node = blockIdx.x * 4 + (threadIdx.x >> 6);
    int L = threadIdx.x & 63;
    bool act = L < 40;
    int col = act ? L : 0;
    int b = row_start[node], e = row_start[node + 1];
    float ad = adst[node];

    float a0 = 0.f, a1 = 0.f, a2 = 0.f, a3 = 0.f;
    float d0 = 0.f, d1 = 0.f, d2 = 0.f, d3 = 0.f;

    int j = b;
    for (; j + 3 < e; j += 4) {
        int s0 = csr_src[j], s1 = csr_src[j + 1], s2 = csr_src[j + 2], s3 = csr_src[j + 3];
        float w0 = wexp(asrc[s0] + ad);
        float w1 = wexp(asrc[s1] + ad);
        float w2 = wexp(asrc[s2] + ad);
        float w3 = wexp(asrc[s3] + ad);
        float x0 = __half2float(h2h[(size_t)s0 * 64 + col]);
        float x1 = __half2float(h2h[(size_t)s1 * 64 + col]);
        float x2 = __half2float(h2h[(size_t)s2 * 64 + col]);
        float x3 = __half2float(h2h[(size_t)s3 * 64 + col]);
        a0 += w0 * x0; d0 += w0;
        a1 += w1 * x1; d1 += w1;
        a2 += w2 * x2; d2 += w2;
        a3 += w3 * x3; d3 += w3;
    }
    for (; j < e; ++j) {
        int s = csr_src[j];
        float w = wexp(asrc[s] + ad);
        float xv = __half2float(h2h[(size_t)s * 64 + col]);
        a0 += w * xv; d0 += w;
    }

    float den = (d0 + d1) + (d2 + d3);
    float acc = (a0 + a1) + (a2 + a3);
    float v = act ? acc / (den + 1e-16f) + b2[L] : -1e30f;
    float mx = v;
#pragma unroll
    for (int off = 32; off; off >>= 1) mx = fmaxf(mx, __shfl_xor(mx, off));
    float ex = act ? __expf(v - mx) : 0.f;
#pragma unroll
    for (int off = 32; off; off >>= 1) ex += __shfl_xor(ex, off);
    if (act) out[(size_t)node * 40 + L] = v - mx - logf(ex);
}

// ---------------------------------------------------------------------------
extern "C" void kernel_launch(void* const* d_in, const int* in_sizes, int n_in,
                              void* d_out, int out_size, void* d_ws, size_t ws_size,
                              hipStream_t stream)
{
    const float* x   = (const float*)d_in[0];
    const int*   ei  = (const int*)d_in[1];
    const float* W1  = (const float*)d_in[2];
    const float* as1 = (const float*)d_in[3];
    const float* ad1 = (const float*)d_in[4];
    const float* b1  = (const float*)d_in[5];
    const float* W2  = (const float*)d_in[6];
    const float* as2 = (const float*)d_in[7];
    const float* ad2 = (const float*)d_in[8];
    const float* b2  = (const float*)d_in[9];
    float* out = (float*)d_out;

    float* ws = (float*)d_ws;
    // workspace layout (4B units); total ~23.8M = 95.2 MB
    __half* h1h   = (__half*)ws;                  // N*128 halves; reused as h2h (N*64 halves)
    __half* out1h = (__half*)(ws + 6400000);      // N*128 halves
    float* asrc1 = ws + 19200000;                 // 2N
    float* adst1 = ws + 19400000;                 // 2N
    float* asrc2 = ws + 19600000;                 // N
    float* adst2 = ws + 19700000;                 // N
    int* bcur      = (int*)(ws + 19800000);       // NB
    int* bbase     = (int*)(ws + 19801000);       // NB
    int* row_start = (int*)(ws + 19802000);       // N+1
    int* csr_src   = (int*)(ws + 19910000);       // E_TOT
    unsigned* bdata = (unsigned*)(ws + 21700000); // NB*BCAP = 2.1M

    // zero bucket cursors only (2 KB)
    hipMemsetAsync(bcur, 0, NB * sizeof(int), stream);

    // CSR build: bin -> scan -> build
    bin_k<<<NBIN_WG, 256, 0, stream>>>(ei, bcur, bdata);
    scanb_k<<<1, 512, 0, stream>>>(bcur, bbase);
    build_k<<<NB, 256, 0, stream>>>(bdata, bcur, bbase, row_start, csr_src);

    // layer 1
    gemm1_k<<<1563, 256, 0, stream>>>(x, W1, as1, ad1, h1h, asrc1, adst1);
    fagg1_k<<<25000, 256, 0, stream>>>(csr_src, row_start, asrc1, adst1, h1h, b1, out1h);

    // layer 2 (h2h reuses h1h region, stride 64 halves = one 128B line)
    __half* h2h = h1h;
    gemm2_k<<<1563, 256, 0, stream>>>(out1h, W2, as2, ad2, h2h, asrc2, adst2);
    fagg2_k<<<25000, 256, 0, stream>>>(csr_src, row_start, asrc2, adst2, h2h, b2, out);
}